// Round 1
// baseline (144.207 us; speedup 1.0000x reference)
//
#include <hip/hip_runtime.h>

#define NBLOCKS 1024
#define NTHREADS 256

__device__ __forceinline__ float wave_reduce(float v) {
    #pragma unroll
    for (int off = 32; off > 0; off >>= 1) v += __shfl_down(v, off, 64);
    return v;
}

__global__ __launch_bounds__(NTHREADS) void dis_partial_kernel(
    const float* __restrict__ pred, const float* __restrict__ targ,
    float* __restrict__ partials, int nquad, int ntrip) {
    const int tid = blockIdx.x * NTHREADS + threadIdx.x;
    const int stride = gridDim.x * NTHREADS;
    float acc = 0.f;

    const float4* p4 = (const float4*)pred;
    const float4* t4 = (const float4*)targ;

    // Each iteration: 4 triples = 12 floats = 3 float4 loads per input.
    for (int i = tid; i < nquad; i += stride) {
        float4 pa = p4[3 * i + 0];
        float4 pb = p4[3 * i + 1];
        float4 pc = p4[3 * i + 2];
        float4 ta = t4[3 * i + 0];
        float4 tb = t4[3 * i + 1];
        float4 tc = t4[3 * i + 2];

        float dx, dy, dz;
        dx = pa.x - ta.x; dy = pa.y - ta.y; dz = pa.z - ta.z;
        acc += sqrtf(dx * dx + dy * dy + dz * dz);
        dx = pa.w - ta.w; dy = pb.x - tb.x; dz = pb.y - tb.y;
        acc += sqrtf(dx * dx + dy * dy + dz * dz);
        dx = pb.z - tb.z; dy = pb.w - tb.w; dz = pc.x - tc.x;
        acc += sqrtf(dx * dx + dy * dy + dz * dz);
        dx = pc.y - tc.y; dy = pc.z - tc.z; dz = pc.w - tc.w;
        acc += sqrtf(dx * dx + dy * dy + dz * dz);
    }

    // Scalar tail for any triples not covered by the quad loop (none for
    // B=262144, but keep it correct for any n divisible by 3).
    for (int j = 4 * nquad + tid; j < ntrip; j += stride) {
        float dx = pred[3 * j + 0] - targ[3 * j + 0];
        float dy = pred[3 * j + 1] - targ[3 * j + 1];
        float dz = pred[3 * j + 2] - targ[3 * j + 2];
        acc += sqrtf(dx * dx + dy * dy + dz * dz);
    }

    acc = wave_reduce(acc);

    __shared__ float smem[NTHREADS / 64];
    const int lane = threadIdx.x & 63;
    const int wave = threadIdx.x >> 6;
    if (lane == 0) smem[wave] = acc;
    __syncthreads();
    if (threadIdx.x == 0) {
        float s = 0.f;
        #pragma unroll
        for (int w = 0; w < NTHREADS / 64; ++w) s += smem[w];
        partials[blockIdx.x] = s;
    }
}

__global__ __launch_bounds__(NTHREADS) void dis_finalize_kernel(
    const float* __restrict__ partials, float* __restrict__ out,
    int nblocks, float scale) {
    float acc = 0.f;
    for (int i = threadIdx.x; i < nblocks; i += NTHREADS) acc += partials[i];
    acc = wave_reduce(acc);

    __shared__ float smem[NTHREADS / 64];
    const int lane = threadIdx.x & 63;
    const int wave = threadIdx.x >> 6;
    if (lane == 0) smem[wave] = acc;
    __syncthreads();
    if (threadIdx.x == 0) {
        float s = 0.f;
        #pragma unroll
        for (int w = 0; w < NTHREADS / 64; ++w) s += smem[w];
        out[0] = s * scale;  // full overwrite: d_out is poisoned before timed runs
    }
}

extern "C" void kernel_launch(void* const* d_in, const int* in_sizes, int n_in,
                              void* d_out, int out_size, void* d_ws, size_t ws_size,
                              hipStream_t stream) {
    const float* pred = (const float*)d_in[0];
    const float* targ = (const float*)d_in[1];
    float* out = (float*)d_out;
    float* partials = (float*)d_ws;  // NBLOCKS floats, each block owns its slot

    const int n = in_sizes[0];       // B * 63 = 16,515,072
    const int ntrip = n / 3;         // number of joint distances
    const int nquad = n / 12;        // quad-triple work items (exact here)
    const float scale = 1.0f / (float)ntrip;

    dis_partial_kernel<<<NBLOCKS, NTHREADS, 0, stream>>>(pred, targ, partials,
                                                         nquad, ntrip);
    dis_finalize_kernel<<<1, NTHREADS, 0, stream>>>(partials, out, NBLOCKS, scale);
}

// Round 2
// 143.227 us; speedup vs baseline: 1.0068x; 1.0068x over previous
//
#include <hip/hip_runtime.h>

#define NTHREADS 256
#define NBLOCKS 1792              // 7 blocks/CU on 256 CUs; 5376 tiles / 1792 = 3 each
#define TILE_F4 768               // 256 threads x 3 float4
#define TILE_FLOATS 3072
#define TILE_TRIPLES 1024

__device__ __forceinline__ float wave_reduce(float v) {
    #pragma unroll
    for (int off = 32; off > 0; off >>= 1) v += __shfl_down(v, off, 64);
    return v;
}

__device__ __forceinline__ float block_reduce(float v) {
    v = wave_reduce(v);
    __shared__ float smem[NTHREADS / 64];
    const int lane = threadIdx.x & 63;
    const int wave = threadIdx.x >> 6;
    if (lane == 0) smem[wave] = v;
    __syncthreads();
    float s = 0.f;
    if (threadIdx.x == 0) {
        #pragma unroll
        for (int w = 0; w < NTHREADS / 64; ++w) s += smem[w];
    }
    return s;
}

__global__ __launch_bounds__(NTHREADS) void dis_partial_kernel(
    const float4* __restrict__ p4, const float4* __restrict__ t4,
    const float* __restrict__ pred, const float* __restrict__ targ,
    float* __restrict__ partials, int ntile, int ntrip) {
    __shared__ float diff[TILE_FLOATS];
    const int t = threadIdx.x;
    float acc = 0.f;

    for (int tile = blockIdx.x; tile < ntile; tile += gridDim.x) {
        const int base = tile * TILE_F4;
        // Coalesced stage: lane stride = 16 B, subtract at load, store diff.
        #pragma unroll
        for (int j = 0; j < 3; ++j) {
            const int idx = base + j * NTHREADS + t;
            float4 p = p4[idx];
            float4 q = t4[idx];
            float4 d;
            d.x = p.x - q.x; d.y = p.y - q.y; d.z = p.z - q.z; d.w = p.w - q.w;
            ((float4*)diff)[j * NTHREADS + t] = d;
        }
        __syncthreads();
        // Re-read as triples: word addr = 3*(j*256+t) -> lane stride 3 words,
        // lanes l and l+32 alias 2-way per bank (free on gfx950).
        #pragma unroll
        for (int j = 0; j < 4; ++j) {
            const int tr = j * NTHREADS + t;
            const float dx = diff[3 * tr + 0];
            const float dy = diff[3 * tr + 1];
            const float dz = diff[3 * tr + 2];
            acc += sqrtf(dx * dx + dy * dy + dz * dz);
        }
        __syncthreads();
    }

    // Generic scalar tail (empty for B=262144: 5376 tiles exactly).
    for (int j = ntile * TILE_TRIPLES + blockIdx.x * NTHREADS + t; j < ntrip;
         j += gridDim.x * NTHREADS) {
        const float dx = pred[3 * j + 0] - targ[3 * j + 0];
        const float dy = pred[3 * j + 1] - targ[3 * j + 1];
        const float dz = pred[3 * j + 2] - targ[3 * j + 2];
        acc += sqrtf(dx * dx + dy * dy + dz * dz);
    }

    const float s = block_reduce(acc);
    if (threadIdx.x == 0) partials[blockIdx.x] = s;
}

__global__ __launch_bounds__(NTHREADS) void dis_finalize_kernel(
    const float* __restrict__ partials, float* __restrict__ out,
    int nblocks, float scale) {
    float acc = 0.f;
    for (int i = threadIdx.x; i < nblocks; i += NTHREADS) acc += partials[i];
    const float s = block_reduce(acc);
    if (threadIdx.x == 0) out[0] = s * scale;  // full overwrite of poisoned d_out
}

extern "C" void kernel_launch(void* const* d_in, const int* in_sizes, int n_in,
                              void* d_out, int out_size, void* d_ws, size_t ws_size,
                              hipStream_t stream) {
    const float* pred = (const float*)d_in[0];
    const float* targ = (const float*)d_in[1];
    float* out = (float*)d_out;
    float* partials = (float*)d_ws;  // NBLOCKS floats, each block owns its slot

    const int n = in_sizes[0];              // B * 63 = 16,515,072
    const int ntrip = n / 3;                // 5,505,024 joint distances
    const int ntile = n / TILE_FLOATS;      // 5376 full tiles (exact here)
    const float scale = 1.0f / (float)ntrip;

    dis_partial_kernel<<<NBLOCKS, NTHREADS, 0, stream>>>(
        (const float4*)pred, (const float4*)targ, pred, targ, partials, ntile, ntrip);
    dis_finalize_kernel<<<1, NTHREADS, 0, stream>>>(partials, out, NBLOCKS, scale);
}